// Round 18
// baseline (668.369 us; speedup 1.0000x reference)
//
#include <hip/hip_runtime.h>

#define DEVI __device__ __forceinline__

typedef __attribute__((ext_vector_type(4))) float  f32x4;
typedef __attribute__((ext_vector_type(8))) short  s16x8;
typedef __attribute__((ext_vector_type(4))) short  s16x4;
typedef __attribute__((ext_vector_type(8))) __bf16 bf16x8;

constexpr int  Nn  = 12288;
constexpr int  NP  = 12296;          // padded rows per batch (4 + 12288 + 4)
constexpr long TOK = 98304;          // B*D*N

DEVI short f2bf(float f) {           // fp32 -> bf16 (RTNE), bits as short
  unsigned u = __builtin_bit_cast(unsigned, f);
  u += 0x7fffu + ((u >> 16) & 1u);
  return (short)(u >> 16);
}

DEVI float fast_gelu(float v) {      // == 0.5v(1+tanh(.79788(v+.044715v^3)))
  const float a = 1.5957691216f * (v + 0.044715f * v * v * v);
  return v / (1.0f + __expf(-a));    // sigmoid identity; safe for all |v|
}

DEVI f32x4 MFMA(s16x8 a, s16x8 b, f32x4 c) {
  return __builtin_amdgcn_mfma_f32_16x16x32_bf16(
      __builtin_bit_cast(bf16x8, a), __builtin_bit_cast(bf16x8, b), c, 0, 0, 0);
}

DEVI void gld16(const void* g, void* l) {   // global -> LDS, 16B/lane, linear dest
  __builtin_amdgcn_global_load_lds(
      (const __attribute__((address_space(1))) void*)g,
      (__attribute__((address_space(3))) void*)l, 16, 0, 0);
}

// Swizzled stage (T2/G21): linear LDS dest; PRE-SWIZZLED global source.
// LDS slot s of row r holds global 16B-unit s ^ (r&7). Reads use the same XOR.
template <int CNT, int NT>
DEVI void stageS(const short* __restrict__ g_base, long g_row0, int ld, int k0,
                 short* __restrict__ lds, int tid) {
  const int w = tid >> 6;
#pragma unroll
  for (int c = 0; c < CNT; ++c) {
    const int u = c * NT + tid;
    const int row = u >> 3, ch = (u & 7) ^ (row & 7);
    const short* g = g_base + (g_row0 + row) * (long)ld + k0 + ch * 8;
    gld16(g, lds + (c * NT + w * 64) * 8);
  }
}

// ---------------- weight prep + halo-pad zeroing (one launch) ----------------
__global__ void prep_k(const float* __restrict__ qkv_w, const float* __restrict__ proj_w,
                       const float* __restrict__ fc1_w, const float* __restrict__ fc2_w,
                       const float* __restrict__ conv_w,
                       short* __restrict__ qkvWt, short* __restrict__ projWt,
                       short* __restrict__ fc1Wt, short* __restrict__ fc2Wt,
                       short* __restrict__ convWt, short* __restrict__ hp) {
  int idx = blockIdx.x * 256 + threadIdx.x;
  if (idx < 196608) {                 // qkvWt [768][256]
    int o = idx >> 8, i = idx & 255;
    qkvWt[idx] = f2bf(qkv_w[i * 768 + o]);
    return;
  }
  idx -= 196608;
  if (idx < 65536) {                  // projWt [256][256]
    int o = idx >> 8, i = idx & 255;
    projWt[idx] = f2bf(proj_w[i * 256 + o]);
    return;
  }
  idx -= 65536;
  if (idx < 262144) {                 // fc1Wt [1024][256]
    int o = idx >> 8, i = idx & 255;
    fc1Wt[idx] = f2bf(fc1_w[i * 1024 + o]);
    return;
  }
  idx -= 262144;
  if (idx < 262144) {                 // fc2Wt [256][1024]
    int o = idx >> 10, i = idx & 1023;
    fc2Wt[idx] = f2bf(fc2_w[i * 256 + o]);
    return;
  }
  idx -= 262144;
  if (idx < 589824) {                 // convWt [co][k][ci]
    int co = idx / 2304, rem = idx % 2304;
    int k = rem >> 8, ci = rem & 255;
    convWt[idx] = f2bf(conv_w[co * 2304 + ci * 9 + k]);
    return;
  }
  idx -= 589824;
  if (idx < 16384) {                  // zero halo pads of hp
    int b = idx >> 11, rem = idx & 2047;
    int rs = rem >> 8, ch = rem & 255;
    int p = rs < 4 ? rs : 12288 + rs;
    hp[((long)b * NP + p) * 256 + ch] = 0;
  }
}

// ---------------- LayerNorm1 (fp32 in -> bf16 out, padded rows) --------------
__global__ __launch_bounds__(256) void ln_k(const float* __restrict__ x,
                                            const float* __restrict__ gw,
                                            const float* __restrict__ bw,
                                            short* __restrict__ out) {
  const int tid = threadIdx.x, w = tid >> 6, lane = tid & 63;
  const long t = (long)blockIdx.x * 4 + w;
  f32x4 v = *((const f32x4*)(x + t * 256) + lane);
  float s  = v[0] + v[1] + v[2] + v[3];
  float ss = v[0] * v[0] + v[1] * v[1] + v[2] * v[2] + v[3] * v[3];
#pragma unroll
  for (int mk = 1; mk < 64; mk <<= 1) {
    s  += __shfl_xor(s, mk);
    ss += __shfl_xor(ss, mk);
  }
  const float mu   = s * (1.0f / 256.0f);
  const float var  = ss * (1.0f / 256.0f) - mu * mu;
  const float rstd = rsqrtf(var + 1e-5f);
  f32x4 g4 = *((const f32x4*)gw + lane);
  f32x4 b4 = *((const f32x4*)bw + lane);
  const long orow = t + (t / Nn) * 8 + 4;
  s16x4 o4;
#pragma unroll
  for (int j = 0; j < 4; ++j) o4[j] = f2bf((v[j] - mu) * rstd * g4[j] + b4[j]);
  *((s16x4*)(out + orow * 256) + lane) = o4;
}

// -- 256x256 GEMM, 16 waves (4Mx4N, wave=64x64), BK=64, 2-phase, T2-swizzled --
// Squarer tile halves staged bytes/output vs 128x256 (fc1: 590->393 MB).
// Per-wave geometry unchanged from the proven config (acc[4][4], VGPR ~60).
// EPI 0: bf16(acc+bias). EPI 1: fp32 acc+bias+res. EPI 2: bf16(fast_gelu).
template <int EPI>
__global__ __launch_bounds__(1024, 2) void gemm2_k(
    const short* __restrict__ A, int lda,
    const short* __restrict__ Bt,         // [Nout][K] bf16 (pre-transposed)
    const float* __restrict__ bias,
    const float* res, short* outS, float* outF,
    int ldo, int K, int ncol) {
  __shared__ __align__(16) short As[256][64];
  __shared__ __align__(16) short Bs[256][64];
  const int tid = threadIdx.x, w = tid >> 6, lane = tid & 63;
  const int q = lane >> 4, r16 = lane & 15;
  const int W = blockIdx.x, per = gridDim.x >> 3;
  const int L = (W & 7) * per + (W >> 3);         // bijective XCD swizzle
  const long row0 = (long)(L / ncol) * 256;
  const int  col0 = (L % ncol) * 256;
  const int wr = w >> 2, wc = w & 3;              // wave: 64 rows x 64 cols
  f32x4 acc[4][4] = {};

  for (int k0 = 0; k0 < K; k0 += 64) {
    stageS<2, 1024>(A, row0, lda, k0, &As[0][0], tid);
    stageS<2, 1024>(Bt, col0, K, k0, &Bs[0][0], tid);
    __syncthreads();
#pragma unroll
    for (int kk = 0; kk < 2; ++kk) {
      s16x8 af[4], bfv[4];
#pragma unroll
      for (int m = 0; m < 4; ++m) {
        const int ar = wr * 64 + m * 16 + r16;
        af[m] = *(const s16x8*)&As[ar][((kk * 4 + q) ^ (ar & 7)) * 8];
      }
#pragma unroll
      for (int n = 0; n < 4; ++n) {
        const int br = wc * 64 + n * 16 + r16;
        bfv[n] = *(const s16x8*)&Bs[br][((kk * 4 + q) ^ (br & 7)) * 8];
      }
#pragma unroll
      for (int m = 0; m < 4; ++m)
#pragma unroll
        for (int n = 0; n < 4; ++n) acc[m][n] = MFMA(af[m], bfv[n], acc[m][n]);
    }
    __syncthreads();
  }

  const long orow = row0 + wr * 64;
  const int  ocol = col0 + wc * 64;
#pragma unroll
  for (int n = 0; n < 4; ++n) {
    const int   gc = ocol + n * 16 + r16;
    const float bn = bias[gc];
#pragma unroll
    for (int m = 0; m < 4; ++m) {
      const long gr = orow + m * 16 + q * 4;
#pragma unroll
      for (int r = 0; r < 4; ++r) {
        float v = acc[m][n][r] + bn;
        const long o = (gr + r) * (long)ldo + gc;
        if constexpr (EPI == 0) {
          outS[o] = f2bf(v);
        } else if constexpr (EPI == 1) {
          outF[o] = v + res[o];
        } else {
          outS[o] = f2bf(fast_gelu(v));
        }
      }
    }
  }
}

// -- conv1d K=9, BM=256, XOR-swizzled LDS (T2): A halo-staged, B dbuf ---------
__global__ __launch_bounds__(512, 2) void conv_k(const short* __restrict__ hp,
                                                 const short* __restrict__ convWt,
                                                 const float* __restrict__ bias,
                                                 short* __restrict__ out) {
  __shared__ __align__(16) short As[320][64];      // stage writes 320 rows; 264 used
  __shared__ __align__(16) short Bs[2][128][64];
  const int tid = threadIdx.x, w = tid >> 6, lane = tid & 63;
  const int q = lane >> 4, r16 = lane & 15;
  const int W = blockIdx.x, per = gridDim.x >> 3;
  const int L = (W & 7) * per + (W >> 3);
  const long row0 = (long)(L >> 1) * 256;
  const int  col0 = (L & 1) * 128;
  const int  b  = (int)(row0 / Nn);
  const int  n0 = (int)(row0 % Nn);                // 12288 % 256 == 0
  const long abase = (long)b * NP + n0;            // hp row n0+r == token n0+r-4
  const int  wr = w >> 1, wc = w & 1;              // wave: 64 rows x 64 cols
  f32x4 acc[4][4] = {};

  stageS<5, 512>(hp, abase, 256, 0, &As[0][0], tid);
  stageS<2, 512>(convWt, col0, 2304, 0, &Bs[0][0][0], tid);
  __syncthreads();
  int cur = 0;
  for (int k0 = 0; k0 < 256; k0 += 64) {
    for (int tap = 0; tap < 9; ++tap) {
      if (tap < 8)
        stageS<2, 512>(convWt, col0, 2304, (tap + 1) * 256 + k0, &Bs[cur ^ 1][0][0], tid);
      else if (k0 + 64 < 256)
        stageS<2, 512>(convWt, col0, 2304, k0 + 64, &Bs[cur ^ 1][0][0], tid);
#pragma unroll
      for (int kk = 0; kk < 2; ++kk) {
        s16x8 af[4], bfv[4];
#pragma unroll
        for (int m = 0; m < 4; ++m) {
          const int tr = tap + wr * 64 + m * 16 + r16;
          af[m] = *(const s16x8*)&As[tr][((kk * 4 + q) ^ (tr & 7)) * 8];
        }
#pragma unroll
        for (int n = 0; n < 4; ++n) {
          const int br = wc * 64 + n * 16 + r16;
          bfv[n] = *(const s16x8*)&Bs[cur][br][((kk * 4 + q) ^ (br & 7)) * 8];
        }
#pragma unroll
        for (int m = 0; m < 4; ++m)
#pragma unroll
          for (int n = 0; n < 4; ++n) acc[m][n] = MFMA(af[m], bfv[n], acc[m][n]);
      }
      __syncthreads();
      cur ^= 1;
    }
    if (k0 + 64 < 256) {
      stageS<5, 512>(hp, abase, 256, k0 + 64, &As[0][0], tid);
      __syncthreads();
    }
  }

  const long orow = row0 + wr * 64;
  const int  ocol = col0 + wc * 64;
#pragma unroll
  for (int n = 0; n < 4; ++n) {
    const int   gc = ocol + n * 16 + r16;
    const float bn = bias[gc];
#pragma unroll
    for (int m = 0; m < 4; ++m) {
      const long gr = orow + m * 16 + q * 4;
#pragma unroll
      for (int r = 0; r < 4; ++r) out[(gr + r) * 256L + gc] = f2bf(acc[m][n][r] + bn);
    }
  }
}

// ------- proj GEMM (128x256 tile, 8 waves) + residual + fused LayerNorm2 -----
__global__ __launch_bounds__(512, 4) void proj_ln_k(
    const short* __restrict__ A,
    const short* __restrict__ Bt,
    const float* __restrict__ bias,
    const float* __restrict__ res,
    const float* __restrict__ gw, const float* __restrict__ bw,
    float* __restrict__ x1,
    short* __restrict__ lnout) {
  __shared__ __align__(16) short As[128][64];
  __shared__ __align__(16) short Bs[256][64];
  __shared__ float red[4][128][2];
  const int tid = threadIdx.x, w = tid >> 6, lane = tid & 63;
  const int q = lane >> 4, r16 = lane & 15;
  const int W = blockIdx.x, per = gridDim.x >> 3;
  const long row0 = (long)((W & 7) * per + (W >> 3)) * 128;
  const int wr = w >> 2, wc = w & 3;
  f32x4 acc[4][4] = {};

  for (int k0 = 0; k0 < 256; k0 += 64) {
    stageS<2, 512>(A, row0, 256, k0, &As[0][0], tid);
    stageS<4, 512>(Bt, 0, 256, k0, &Bs[0][0], tid);
    __syncthreads();
#pragma unroll
    for (int kk = 0; kk < 2; ++kk) {
      s16x8 af[4], bfv[4];
#pragma unroll
      for (int m = 0; m < 4; ++m) {
        const int ar = wr * 64 + m * 16 + r16;
        af[m] = *(const s16x8*)&As[ar][((kk * 4 + q) ^ (ar & 7)) * 8];
      }
#pragma unroll
      for (int n = 0; n < 4; ++n) {
        const int br = wc * 64 + n * 16 + r16;
        bfv[n] = *(const s16x8*)&Bs[br][((kk * 4 + q) ^ (br & 7)) * 8];
      }
#pragma unroll
      for (int m = 0; m < 4; ++m)
#pragma unroll
        for (int n = 0; n < 4; ++n) acc[m][n] = MFMA(af[m], bfv[n], acc[m][n]);
    }
    __syncthreads();
  }

  float biasr[4], gv[4], bv[4];
#pragma unroll
  for (int n = 0; n < 4; ++n) {
    const int gc = wc * 64 + n * 16 + r16;
    biasr[n] = bias[gc]; gv[n] = gw[gc]; bv[n] = bw[gc];
  }

#pragma unroll
  for (int m = 0; m < 4; ++m) {
#pragma unroll
    for (int r = 0; r < 4; ++r) {
      const long gr = row0 + wr * 64 + m * 16 + q * 4 + r;
      float s = 0.f, ss = 0.f;
#pragma unroll
      for (int n = 0; n < 4; ++n) {
        const int gc = wc * 64 + n * 16 + r16;
        float v = acc[m][n][r] + biasr[n] + res[gr * 256 + gc];
        acc[m][n][r] = v;
        x1[gr * 256 + gc] = v;
        s += v; ss += v * v;
      }
#pragma unroll
      for (int mk = 1; mk < 16; mk <<= 1) {
        s  += __shfl_xor(s, mk);
        ss += __shfl_xor(ss, mk);
      }
      if (r16 == 0) {
        const int lr = wr * 64 + m * 16 + q * 4 + r;
        red[wc][lr][0] = s;
        red[wc][lr][1] = ss;
      }
    }
  }
  __syncthreads();

#pragma unroll
  for (int m = 0; m < 4; ++m) {
#pragma unroll
    for (int r = 0; r < 4; ++r) {
      const int  lr = wr * 64 + m * 16 + q * 4 + r;
      const long gr = row0 + lr;
      const float S  = red[0][lr][0] + red[1][lr][0] + red[2][lr][0] + red[3][lr][0];
      const float SS = red[0][lr][1] + red[1][lr][1] + red[2][lr][1] + red[3][lr][1];
      const float mu = S * (1.0f / 256.0f);
      const float rstd = rsqrtf(SS * (1.0f / 256.0f) - mu * mu + 1e-5f);
#pragma unroll
      for (int n = 0; n < 4; ++n) {
        const int gc = wc * 64 + n * 16 + r16;
        lnout[gr * 256 + gc] = f2bf((acc[m][n][r] - mu) * rstd * gv[n] + bv[n]);
      }
    }
  }
}

// ---------------- windowed attention: one wave per (window, head) ------------
__global__ __launch_bounds__(256, 2) void attn_k(const short* __restrict__ qkv,
                                                 short* __restrict__ o) {
  __shared__ __align__(16) short Pt[4][64][68];
  __shared__ __align__(16) short Vs[4][64][32];
  const int tid = threadIdx.x, w = tid >> 6, lane = tid & 63;
  const int q = lane >> 4, r16 = lane & 15;
  const int job = blockIdx.x * 4 + w;
  const int win = job >> 3, h = job & 7;
  const short* base = qkv + (long)win * 64 * 768;

#pragma unroll
  for (int c = 0; c < 4; ++c) {
    const int idx16 = c * 64 + lane;
    const short* g = base + (long)(idx16 >> 2) * 768 + 512 + h * 32 + (idx16 & 3) * 8;
    gld16(g, (char*)&Vs[w][0][0] + c * 1024);
  }

  s16x8 aq[4], bk[4];
#pragma unroll
  for (int m = 0; m < 4; ++m)
    aq[m] = *(const s16x8*)(base + (long)(m * 16 + r16) * 768 + h * 32 + q * 8);
#pragma unroll
  for (int n = 0; n < 4; ++n)
    bk[n] = *(const s16x8*)(base + (long)(n * 16 + r16) * 768 + 256 + h * 32 + q * 8);
  f32x4 sc[4][4] = {};
#pragma unroll
  for (int m = 0; m < 4; ++m)
#pragma unroll
    for (int n = 0; n < 4; ++n) sc[m][n] = MFMA(aq[m], bk[n], sc[m][n]);

  const float scale = 0.17677669529663687f;
#pragma unroll
  for (int m = 0; m < 4; ++m) {
#pragma unroll
    for (int r = 0; r < 4; ++r) {
      float a0 = sc[m][0][r] * scale, a1 = sc[m][1][r] * scale;
      float a2 = sc[m][2][r] * scale, a3 = sc[m][3][r] * scale;
      float mx = fmaxf(fmaxf(a0, a1), fmaxf(a2, a3));
      mx = fmaxf(mx, __shfl_xor(mx, 1));
      mx = fmaxf(mx, __shfl_xor(mx, 2));
      mx = fmaxf(mx, __shfl_xor(mx, 4));
      mx = fmaxf(mx, __shfl_xor(mx, 8));
      float e0 = __expf(a0 - mx), e1 = __expf(a1 - mx);
      float e2 = __expf(a2 - mx), e3 = __expf(a3 - mx);
      float sm = e0 + e1 + e2 + e3;
      sm += __shfl_xor(sm, 1);
      sm += __shfl_xor(sm, 2);
      sm += __shfl_xor(sm, 4);
      sm += __shfl_xor(sm, 8);
      float inv = 1.0f / sm;
      sc[m][0][r] = e0 * inv; sc[m][1][r] = e1 * inv;
      sc[m][2][r] = e2 * inv; sc[m][3][r] = e3 * inv;
    }
  }

#pragma unroll
  for (int m = 0; m < 4; ++m)
#pragma unroll
    for (int n = 0; n < 4; ++n) {
      s16x4 p4;
#pragma unroll
      for (int r = 0; r < 4; ++r) p4[r] = f2bf(sc[m][n][r]);
      *(s16x4*)&Pt[w][n * 16 + r16][m * 16 + q * 4] = p4;
    }

  asm volatile("s_waitcnt vmcnt(0)" ::: "memory");

  f32x4 oa[4][2] = {};
#pragma unroll
  for (int ks = 0; ks < 2; ++ks) {
    s16x8 bv[2];
#pragma unroll
    for (int nt = 0; nt < 2; ++nt)
#pragma unroll
      for (int jj = 0; jj < 8; ++jj)
        bv[nt][jj] = Vs[w][ks * 32 + q * 8 + jj][nt * 16 + r16];
#pragma unroll
    for (int m = 0; m < 4; ++m) {
      s16x8 ap;
#pragma unroll
      for (int jj = 0; jj < 8; ++jj)
        ap[jj] = Pt[w][ks * 32 + q * 8 + jj][m * 16 + r16];
#pragma unroll
      for (int nt = 0; nt < 2; ++nt) oa[m][nt] = MFMA(ap, bv[nt], oa[m][nt]);
    }
  }

  short* ob = o + (long)win * 64 * 256 + h * 32;
#pragma unroll
  for (int m = 0; m < 4; ++m)
#pragma unroll
    for (int nt = 0; nt < 2; ++nt)
#pragma unroll
      for (int r = 0; r < 4; ++r)
        ob[(long)(m * 16 + q * 4 + r) * 256 + nt * 16 + r16] = f2bf(oa[m][nt][r]);
}

// -----------------------------------------------------------------------------
extern "C" void kernel_launch(void* const* d_in, const int* in_sizes, int n_in,
                              void* d_out, int out_size, void* d_ws, size_t ws_size,
                              hipStream_t stream) {
  const float* x      = (const float*)d_in[0];
  const float* ln1_g  = (const float*)d_in[1];
  const float* ln1_b  = (const float*)d_in[2];
  const float* conv_w = (const float*)d_in[3];
  const float* conv_b = (const float*)d_in[4];
  const float* qkv_w  = (const float*)d_in[5];
  const float* qkv_b  = (const float*)d_in[6];
  const float* proj_w = (const float*)d_in[7];
  const float* proj_b = (const float*)d_in[8];
  const float* ln2_g  = (const float*)d_in[9];
  const float* ln2_b  = (const float*)d_in[10];
  const float* fc1_w  = (const float*)d_in[11];
  const float* fc1_b  = (const float*)d_in[12];
  const float* fc2_w  = (const float*)d_in[13];
  const float* fc2_b  = (const float*)d_in[14];
  float* out = (float*)d_out;

  constexpr long HPsz = (long)8 * NP * 256;
  constexpr long Qsz  = TOK * 768;
  constexpr long Csz  = TOK * 256;
  short* ws    = (short*)d_ws;
  short* hp    = ws;
  short* qkvB  = ws + HPsz;
  short* cvB   = ws + HPsz + Qsz;
  short* hidB  = qkvB;
  short* wts   = ws + HPsz + Qsz + Csz;
  short* qkvWt  = wts;
  short* projWt = qkvWt + 196608;
  short* fc1Wt  = projWt + 65536;
  short* fc2Wt  = fc1Wt + 262144;
  short* convWt = fc2Wt + 262144;

  prep_k<<<5440, 256, 0, stream>>>(qkv_w, proj_w, fc1_w, fc2_w, conv_w,
                                   qkvWt, projWt, fc1Wt, fc2Wt, convWt, hp);
  // LN1 -> hp (padded layout)
  ln_k<<<24576, 256, 0, stream>>>(x, ln1_g, ln1_b, hp);
  // conv1d -> cvB (bf16): BM=256, swizzled LDS
  conv_k<<<768, 512, 0, stream>>>(hp, convWt, conv_b, cvB);
  // qkv GEMM: 256x256 tiles, 1024 thr, 384 x 3
  gemm2_k<0><<<1152, 1024, 0, stream>>>(cvB, 256, qkvWt, qkv_b,
                                        nullptr, qkvB, nullptr, 768, 256, 3);
  // windowed attention -> hp region (attn_out)
  attn_k<<<3072, 256, 0, stream>>>(qkvB, hp);
  // proj + residual(x) + LN2 fused (swizzled): x1 -> d_out, ln2 -> hp
  proj_ln_k<<<768, 512, 0, stream>>>(hp, projWt, proj_b, x, ln2_g, ln2_b, out, hp);
  // fc1 + fast GELU: 256x256 tiles, 384 x 4
  gemm2_k<2><<<1536, 1024, 0, stream>>>(hp, 256, fc1Wt, fc1_b,
                                        nullptr, hidB, nullptr, 1024, 256, 4);
  // fc2 + residual(x1): 256x256 tiles, 384 x 1, K=1024
  gemm2_k<1><<<384, 1024, 0, stream>>>(hidB, 1024, fc2Wt, fc2_b,
                                       out, nullptr, out, 256, 1024, 1);
}

// Round 19
// 603.607 us; speedup vs baseline: 1.1073x; 1.1073x over previous
//
#include <hip/hip_runtime.h>

#define DEVI __device__ __forceinline__

typedef __attribute__((ext_vector_type(4))) float  f32x4;
typedef __attribute__((ext_vector_type(8))) short  s16x8;
typedef __attribute__((ext_vector_type(4))) short  s16x4;
typedef __attribute__((ext_vector_type(8))) __bf16 bf16x8;

constexpr int  Nn  = 12288;
constexpr int  NP  = 12296;          // padded rows per batch (4 + 12288 + 4)
constexpr long TOK = 98304;          // B*D*N

DEVI short f2bf(float f) {           // fp32 -> bf16 (RTNE), bits as short
  unsigned u = __builtin_bit_cast(unsigned, f);
  u += 0x7fffu + ((u >> 16) & 1u);
  return (short)(u >> 16);
}

DEVI float fast_gelu(float v) {      // == 0.5v(1+tanh(.79788(v+.044715v^3)))
  const float a = 1.5957691216f * (v + 0.044715f * v * v * v);
  return v / (1.0f + __expf(-a));    // sigmoid identity; safe for all |v|
}

DEVI f32x4 MFMA(s16x8 a, s16x8 b, f32x4 c) {
  return __builtin_amdgcn_mfma_f32_16x16x32_bf16(
      __builtin_bit_cast(bf16x8, a), __builtin_bit_cast(bf16x8, b), c, 0, 0, 0);
}

DEVI void gld16(const void* g, void* l) {   // global -> LDS, 16B/lane, linear dest
  __builtin_amdgcn_global_load_lds(
      (const __attribute__((address_space(1))) void*)g,
      (__attribute__((address_space(3))) void*)l, 16, 0, 0);
}

// Stage CNT*NT 16B-units into LDS (8 units per 64-col bf16 row), linear.
template <int CNT, int NT>
DEVI void stageG(const short* __restrict__ g_base, long g_row0, int ld, int k0,
                 short* __restrict__ lds, int tid) {
  const int w = tid >> 6;
#pragma unroll
  for (int c = 0; c < CNT; ++c) {
    const int u = c * NT + tid;
    const int row = u >> 3, ch = u & 7;
    const short* g = g_base + (g_row0 + row) * (long)ld + k0 + ch * 8;
    gld16(g, lds + (c * NT + w * 64) * 8);
  }
}

// Swizzled stage (T2/G21): linear LDS dest; PRE-SWIZZLED global source.
// LDS slot s of row r holds global 16B-unit s ^ (r&7). Reads use the same XOR.
template <int CNT, int NT>
DEVI void stageS(const short* __restrict__ g_base, long g_row0, int ld, int k0,
                 short* __restrict__ lds, int tid) {
  const int w = tid >> 6;
#pragma unroll
  for (int c = 0; c < CNT; ++c) {
    const int u = c * NT + tid;
    const int row = u >> 3, ch = (u & 7) ^ (row & 7);
    const short* g = g_base + (g_row0 + row) * (long)ld + k0 + ch * 8;
    gld16(g, lds + (c * NT + w * 64) * 8);
  }
}

DEVI void xcd_decode(int W, int total, int ncol, long& row0, int& col0, int bm) {
  const int per = total >> 3;
  const int L = (W & 7) * per + (W >> 3);
  row0 = (long)(L / ncol) * bm;
  col0 = (L % ncol) * 128;
}

// ---------------- weight prep + halo-pad zeroing (one launch) ----------------
__global__ void prep_k(const float* __restrict__ qkv_w, const float* __restrict__ proj_w,
                       const float* __restrict__ fc1_w, const float* __restrict__ fc2_w,
                       const float* __restrict__ conv_w,
                       short* __restrict__ qkvWt, short* __restrict__ projWt,
                       short* __restrict__ fc1Wt, short* __restrict__ fc2Wt,
                       short* __restrict__ convWt, short* __restrict__ hp) {
  int idx = blockIdx.x * 256 + threadIdx.x;
  if (idx < 196608) {                 // qkvWt [768][256]
    int o = idx >> 8, i = idx & 255;
    qkvWt[idx] = f2bf(qkv_w[i * 768 + o]);
    return;
  }
  idx -= 196608;
  if (idx < 65536) {                  // projWt [256][256]
    int o = idx >> 8, i = idx & 255;
    projWt[idx] = f2bf(proj_w[i * 256 + o]);
    return;
  }
  idx -= 65536;
  if (idx < 262144) {                 // fc1Wt [1024][256]
    int o = idx >> 8, i = idx & 255;
    fc1Wt[idx] = f2bf(fc1_w[i * 1024 + o]);
    return;
  }
  idx -= 262144;
  if (idx < 262144) {                 // fc2Wt [256][1024]
    int o = idx >> 10, i = idx & 1023;
    fc2Wt[idx] = f2bf(fc2_w[i * 256 + o]);
    return;
  }
  idx -= 262144;
  if (idx < 589824) {                 // convWt [co][k][ci]
    int co = idx / 2304, rem = idx % 2304;
    int k = rem >> 8, ci = rem & 255;
    convWt[idx] = f2bf(conv_w[co * 2304 + ci * 9 + k]);
    return;
  }
  idx -= 589824;
  if (idx < 16384) {                  // zero halo pads of hp
    int b = idx >> 11, rem = idx & 2047;
    int rs = rem >> 8, ch = rem & 255;
    int p = rs < 4 ? rs : 12288 + rs;
    hp[((long)b * NP + p) * 256 + ch] = 0;
  }
}

// ---------------- LayerNorm1 (fp32 in -> bf16 out, padded rows) --------------
__global__ __launch_bounds__(256) void ln_k(const float* __restrict__ x,
                                            const float* __restrict__ gw,
                                            const float* __restrict__ bw,
                                            short* __restrict__ out) {
  const int tid = threadIdx.x, w = tid >> 6, lane = tid & 63;
  const long t = (long)blockIdx.x * 4 + w;
  f32x4 v = *((const f32x4*)(x + t * 256) + lane);
  float s  = v[0] + v[1] + v[2] + v[3];
  float ss = v[0] * v[0] + v[1] * v[1] + v[2] * v[2] + v[3] * v[3];
#pragma unroll
  for (int mk = 1; mk < 64; mk <<= 1) {
    s  += __shfl_xor(s, mk);
    ss += __shfl_xor(ss, mk);
  }
  const float mu   = s * (1.0f / 256.0f);
  const float var  = ss * (1.0f / 256.0f) - mu * mu;
  const float rstd = rsqrtf(var + 1e-5f);
  f32x4 g4 = *((const f32x4*)gw + lane);
  f32x4 b4 = *((const f32x4*)bw + lane);
  const long orow = t + (t / Nn) * 8 + 4;
  s16x4 o4;
#pragma unroll
  for (int j = 0; j < 4; ++j) o4[j] = f2bf((v[j] - mu) * rstd * g4[j] + b4[j]);
  *((s16x4*)(out + orow * 256) + lane) = o4;
}

// -- 256x128 GEMM, 8 waves (4Mx2N, wave=64x64), BK=64, 2-phase, T2-swizzled ---
// Measured-best configuration (609.7 us total). launch_bounds (512,2): VGPR 60,
// no spill. Do NOT raise the 2nd arg (r15: (512,6) => spill, 3x slower).
// EPI 0: bf16(acc+bias). EPI 1: fp32 acc+bias+res. EPI 2: bf16(fast_gelu).
template <int EPI>
__global__ __launch_bounds__(512, 2) void gemm_k(
    const short* __restrict__ A, int lda,
    const short* __restrict__ Bt,         // [Nout][K] bf16 (pre-transposed)
    const float* __restrict__ bias,
    const float* res, short* outS, float* outF,
    int ldo, int K, int ncol) {
  __shared__ __align__(16) short As[256][64];
  __shared__ __align__(16) short Bs[128][64];
  const int tid = threadIdx.x, w = tid >> 6, lane = tid & 63;
  const int q = lane >> 4, r16 = lane & 15;
  long row0; int col0;
  xcd_decode(blockIdx.x, gridDim.x, ncol, row0, col0, 256);
  const int wr = w >> 1, wc = w & 1;       // wave: 64 rows x 64 cols
  f32x4 acc[4][4] = {};

  for (int k0 = 0; k0 < K; k0 += 64) {
    stageS<4, 512>(A, row0, lda, k0, &As[0][0], tid);
    stageS<2, 512>(Bt, col0, K, k0, &Bs[0][0], tid);
    __syncthreads();
#pragma unroll
    for (int kk = 0; kk < 2; ++kk) {
      s16x8 af[4], bfv[4];
#pragma unroll
      for (int m = 0; m < 4; ++m) {
        const int ar = wr * 64 + m * 16 + r16;
        af[m] = *(const s16x8*)&As[ar][((kk * 4 + q) ^ (ar & 7)) * 8];
      }
#pragma unroll
      for (int n = 0; n < 4; ++n) {
        const int br = wc * 64 + n * 16 + r16;
        bfv[n] = *(const s16x8*)&Bs[br][((kk * 4 + q) ^ (br & 7)) * 8];
      }
#pragma unroll
      for (int m = 0; m < 4; ++m)
#pragma unroll
        for (int n = 0; n < 4; ++n) acc[m][n] = MFMA(af[m], bfv[n], acc[m][n]);
    }
    __syncthreads();
  }

  const long orow = row0 + wr * 64;
  const int  ocol = col0 + wc * 64;
#pragma unroll
  for (int n = 0; n < 4; ++n) {
    const int   gc = ocol + n * 16 + r16;
    const float bn = bias[gc];
#pragma unroll
    for (int m = 0; m < 4; ++m) {
      const long gr = orow + m * 16 + q * 4;
#pragma unroll
      for (int r = 0; r < 4; ++r) {
        float v = acc[m][n][r] + bn;
        const long o = (gr + r) * (long)ldo + gc;
        if constexpr (EPI == 0) {
          outS[o] = f2bf(v);
        } else if constexpr (EPI == 1) {
          outF[o] = v + res[o];
        } else {
          outS[o] = f2bf(fast_gelu(v));
        }
      }
    }
  }
}

// -- conv1d K=9, BM=256, XOR-swizzled LDS (T2): A halo-staged, B dbuf ---------
__global__ __launch_bounds__(512, 2) void conv_k(const short* __restrict__ hp,
                                                 const short* __restrict__ convWt,
                                                 const float* __restrict__ bias,
                                                 short* __restrict__ out) {
  __shared__ __align__(16) short As[320][64];      // stage writes 320 rows; 264 used
  __shared__ __align__(16) short Bs[2][128][64];
  const int tid = threadIdx.x, w = tid >> 6, lane = tid & 63;
  const int q = lane >> 4, r16 = lane & 15;
  long row0; int col0;
  xcd_decode(blockIdx.x, gridDim.x, 2, row0, col0, 256);
  const int  b  = (int)(row0 / Nn);
  const int  n0 = (int)(row0 % Nn);                // 12288 % 256 == 0
  const long abase = (long)b * NP + n0;            // hp row n0+r == token n0+r-4
  const int  wr = w >> 1, wc = w & 1;              // wave: 64 rows x 64 cols
  f32x4 acc[4][4] = {};

  stageS<5, 512>(hp, abase, 256, 0, &As[0][0], tid);
  stageS<2, 512>(convWt, col0, 2304, 0, &Bs[0][0][0], tid);
  __syncthreads();
  int cur = 0;
  for (int k0 = 0; k0 < 256; k0 += 64) {
    for (int tap = 0; tap < 9; ++tap) {
      if (tap < 8)
        stageS<2, 512>(convWt, col0, 2304, (tap + 1) * 256 + k0, &Bs[cur ^ 1][0][0], tid);
      else if (k0 + 64 < 256)
        stageS<2, 512>(convWt, col0, 2304, k0 + 64, &Bs[cur ^ 1][0][0], tid);
#pragma unroll
      for (int kk = 0; kk < 2; ++kk) {
        s16x8 af[4], bfv[4];
#pragma unroll
        for (int m = 0; m < 4; ++m) {
          const int tr = tap + wr * 64 + m * 16 + r16;
          af[m] = *(const s16x8*)&As[tr][((kk * 4 + q) ^ (tr & 7)) * 8];
        }
#pragma unroll
        for (int n = 0; n < 4; ++n) {
          const int br = wc * 64 + n * 16 + r16;
          bfv[n] = *(const s16x8*)&Bs[cur][br][((kk * 4 + q) ^ (br & 7)) * 8];
        }
#pragma unroll
        for (int m = 0; m < 4; ++m)
#pragma unroll
          for (int n = 0; n < 4; ++n) acc[m][n] = MFMA(af[m], bfv[n], acc[m][n]);
      }
      __syncthreads();
      cur ^= 1;
    }
    if (k0 + 64 < 256) {
      stageS<5, 512>(hp, abase, 256, k0 + 64, &As[0][0], tid);
      __syncthreads();
    }
  }

  const long orow = row0 + wr * 64;
  const int  ocol = col0 + wc * 64;
#pragma unroll
  for (int n = 0; n < 4; ++n) {
    const int   gc = ocol + n * 16 + r16;
    const float bn = bias[gc];
#pragma unroll
    for (int m = 0; m < 4; ++m) {
      const long gr = orow + m * 16 + q * 4;
#pragma unroll
      for (int r = 0; r < 4; ++r) out[(gr + r) * 256L + gc] = f2bf(acc[m][n][r] + bn);
    }
  }
}

// ------- proj GEMM (128x256 tile, 8 waves) + residual + fused LayerNorm2 -----
__global__ __launch_bounds__(512, 4) void proj_ln_k(
    const short* __restrict__ A,
    const short* __restrict__ Bt,
    const float* __restrict__ bias,
    const float* __restrict__ res,
    const float* __restrict__ gw, const float* __restrict__ bw,
    float* __restrict__ x1,
    short* __restrict__ lnout) {
  __shared__ __align__(16) short As[128][64];
  __shared__ __align__(16) short Bs[256][64];
  __shared__ float red[4][128][2];
  const int tid = threadIdx.x, w = tid >> 6, lane = tid & 63;
  const int q = lane >> 4, r16 = lane & 15;
  const int W = blockIdx.x, per = gridDim.x >> 3;
  const long row0 = (long)((W & 7) * per + (W >> 3)) * 128;
  const int wr = w >> 2, wc = w & 3;
  f32x4 acc[4][4] = {};

  for (int k0 = 0; k0 < 256; k0 += 64) {
    stageG<2, 512>(A, row0, 256, k0, &As[0][0], tid);
    stageG<4, 512>(Bt, 0, 256, k0, &Bs[0][0], tid);
    __syncthreads();
#pragma unroll
    for (int kk = 0; kk < 2; ++kk) {
      s16x8 af[4], bfv[4];
#pragma unroll
      for (int m = 0; m < 4; ++m) af[m] = *(const s16x8*)&As[wr * 64 + m * 16 + r16][kk * 32 + q * 8];
#pragma unroll
      for (int n = 0; n < 4; ++n) bfv[n] = *(const s16x8*)&Bs[wc * 64 + n * 16 + r16][kk * 32 + q * 8];
#pragma unroll
      for (int m = 0; m < 4; ++m)
#pragma unroll
        for (int n = 0; n < 4; ++n) acc[m][n] = MFMA(af[m], bfv[n], acc[m][n]);
    }
    __syncthreads();
  }

  float biasr[4], gv[4], bv[4];
#pragma unroll
  for (int n = 0; n < 4; ++n) {
    const int gc = wc * 64 + n * 16 + r16;
    biasr[n] = bias[gc]; gv[n] = gw[gc]; bv[n] = bw[gc];
  }

#pragma unroll
  for (int m = 0; m < 4; ++m) {
#pragma unroll
    for (int r = 0; r < 4; ++r) {
      const long gr = row0 + wr * 64 + m * 16 + q * 4 + r;
      float s = 0.f, ss = 0.f;
#pragma unroll
      for (int n = 0; n < 4; ++n) {
        const int gc = wc * 64 + n * 16 + r16;
        float v = acc[m][n][r] + biasr[n] + res[gr * 256 + gc];
        acc[m][n][r] = v;
        x1[gr * 256 + gc] = v;
        s += v; ss += v * v;
      }
#pragma unroll
      for (int mk = 1; mk < 16; mk <<= 1) {
        s  += __shfl_xor(s, mk);
        ss += __shfl_xor(ss, mk);
      }
      if (r16 == 0) {
        const int lr = wr * 64 + m * 16 + q * 4 + r;
        red[wc][lr][0] = s;
        red[wc][lr][1] = ss;
      }
    }
  }
  __syncthreads();

#pragma unroll
  for (int m = 0; m < 4; ++m) {
#pragma unroll
    for (int r = 0; r < 4; ++r) {
      const int  lr = wr * 64 + m * 16 + q * 4 + r;
      const long gr = row0 + lr;
      const float S  = red[0][lr][0] + red[1][lr][0] + red[2][lr][0] + red[3][lr][0];
      const float SS = red[0][lr][1] + red[1][lr][1] + red[2][lr][1] + red[3][lr][1];
      const float mu = S * (1.0f / 256.0f);
      const float rstd = rsqrtf(SS * (1.0f / 256.0f) - mu * mu + 1e-5f);
#pragma unroll
      for (int n = 0; n < 4; ++n) {
        const int gc = wc * 64 + n * 16 + r16;
        lnout[gr * 256 + gc] = f2bf((acc[m][n][r] - mu) * rstd * gv[n] + bv[n]);
      }
    }
  }
}

// ---------------- windowed attention: one wave per (window, head) ------------
__global__ __launch_bounds__(256, 2) void attn_k(const short* __restrict__ qkv,
                                                 short* __restrict__ o) {
  __shared__ __align__(16) short Pt[4][64][68];
  __shared__ __align__(16) short Vs[4][64][32];
  const int tid = threadIdx.x, w = tid >> 6, lane = tid & 63;
  const int q = lane >> 4, r16 = lane & 15;
  const int job = blockIdx.x * 4 + w;
  const int win = job >> 3, h = job & 7;
  const short* base = qkv + (long)win * 64 * 768;

#pragma unroll
  for (int c = 0; c < 4; ++c) {
    const int idx16 = c * 64 + lane;
    const short* g = base + (long)(idx16 >> 2) * 768 + 512 + h * 32 + (idx16 & 3) * 8;
    gld16(g, (char*)&Vs[w][0][0] + c * 1024);
  }

  s16x8 aq[4], bk[4];
#pragma unroll
  for (int m = 0; m < 4; ++m)
    aq[m] = *(const s16x8*)(base + (long)(m * 16 + r16) * 768 + h * 32 + q * 8);
#pragma unroll
  for (int n = 0; n < 4; ++n)
    bk[n] = *(const s16x8*)(base + (long)(n * 16 + r16) * 768 + 256 + h * 32 + q * 8);
  f32x4 sc[4][4] = {};
#pragma unroll
  for (int m = 0; m < 4; ++m)
#pragma unroll
    for (int n = 0; n < 4; ++n) sc[m][n] = MFMA(aq[m], bk[n], sc[m][n]);

  const float scale = 0.17677669529663687f;
#pragma unroll
  for (int m = 0; m < 4; ++m) {
#pragma unroll
    for (int r = 0; r < 4; ++r) {
      float a0 = sc[m][0][r] * scale, a1 = sc[m][1][r] * scale;
      float a2 = sc[m][2][r] * scale, a3 = sc[m][3][r] * scale;
      float mx = fmaxf(fmaxf(a0, a1), fmaxf(a2, a3));
      mx = fmaxf(mx, __shfl_xor(mx, 1));
      mx = fmaxf(mx, __shfl_xor(mx, 2));
      mx = fmaxf(mx, __shfl_xor(mx, 4));
      mx = fmaxf(mx, __shfl_xor(mx, 8));
      float e0 = __expf(a0 - mx), e1 = __expf(a1 - mx);
      float e2 = __expf(a2 - mx), e3 = __expf(a3 - mx);
      float sm = e0 + e1 + e2 + e3;
      sm += __shfl_xor(sm, 1);
      sm += __shfl_xor(sm, 2);
      sm += __shfl_xor(sm, 4);
      sm += __shfl_xor(sm, 8);
      float inv = 1.0f / sm;
      sc[m][0][r] = e0 * inv; sc[m][1][r] = e1 * inv;
      sc[m][2][r] = e2 * inv; sc[m][3][r] = e3 * inv;
    }
  }

#pragma unroll
  for (int m = 0; m < 4; ++m)
#pragma unroll
    for (int n = 0; n < 4; ++n) {
      s16x4 p4;
#pragma unroll
      for (int r = 0; r < 4; ++r) p4[r] = f2bf(sc[m][n][r]);
      *(s16x4*)&Pt[w][n * 16 + r16][m * 16 + q * 4] = p4;
    }

  asm volatile("s_waitcnt vmcnt(0)" ::: "memory");

  f32x4 oa[4][2] = {};
#pragma unroll
  for (int ks = 0; ks < 2; ++ks) {
    s16x8 bv[2];
#pragma unroll
    for (int nt = 0; nt < 2; ++nt)
#pragma unroll
      for (int jj = 0; jj < 8; ++jj)
        bv[nt][jj] = Vs[w][ks * 32 + q * 8 + jj][nt * 16 + r16];
#pragma unroll
    for (int m = 0; m < 4; ++m) {
      s16x8 ap;
#pragma unroll
      for (int jj = 0; jj < 8; ++jj)
        ap[jj] = Pt[w][ks * 32 + q * 8 + jj][m * 16 + r16];
#pragma unroll
      for (int nt = 0; nt < 2; ++nt) oa[m][nt] = MFMA(ap, bv[nt], oa[m][nt]);
    }
  }

  short* ob = o + (long)win * 64 * 256 + h * 32;
#pragma unroll
  for (int m = 0; m < 4; ++m)
#pragma unroll
    for (int nt = 0; nt < 2; ++nt)
#pragma unroll
      for (int r = 0; r < 4; ++r)
        ob[(long)(m * 16 + q * 4 + r) * 256 + nt * 16 + r16] = f2bf(oa[m][nt][r]);
}

// -----------------------------------------------------------------------------
extern "C" void kernel_launch(void* const* d_in, const int* in_sizes, int n_in,
                              void* d_out, int out_size, void* d_ws, size_t ws_size,
                              hipStream_t stream) {
  const float* x      = (const float*)d_in[0];
  const float* ln1_g  = (const float*)d_in[1];
  const float* ln1_b  = (const float*)d_in[2];
  const float* conv_w = (const float*)d_in[3];
  const float* conv_b = (const float*)d_in[4];
  const float* qkv_w  = (const float*)d_in[5];
  const float* qkv_b  = (const float*)d_in[6];
  const float* proj_w = (const float*)d_in[7];
  const float* proj_b = (const float*)d_in[8];
  const float* ln2_g  = (const float*)d_in[9];
  const float* ln2_b  = (const float*)d_in[10];
  const float* fc1_w  = (const float*)d_in[11];
  const float* fc1_b  = (const float*)d_in[12];
  const float* fc2_w  = (const float*)d_in[13];
  const float* fc2_b  = (const float*)d_in[14];
  float* out = (float*)d_out;

  constexpr long HPsz = (long)8 * NP * 256;
  constexpr long Qsz  = TOK * 768;
  constexpr long Csz  = TOK * 256;
  short* ws    = (short*)d_ws;
  short* hp    = ws;
  short* qkvB  = ws + HPsz;
  short* cvB   = ws + HPsz + Qsz;
  short* hidB  = qkvB;
  short* wts   = ws + HPsz + Qsz + Csz;
  short* qkvWt  = wts;
  short* projWt = qkvWt + 196608;
  short* fc1Wt  = projWt + 65536;
  short* fc2Wt  = fc1Wt + 262144;
  short* convWt = fc2Wt + 262144;

  prep_k<<<5440, 256, 0, stream>>>(qkv_w, proj_w, fc1_w, fc2_w, conv_w,
                                   qkvWt, projWt, fc1Wt, fc2Wt, convWt, hp);
  // LN1 -> hp (padded layout)
  ln_k<<<24576, 256, 0, stream>>>(x, ln1_g, ln1_b, hp);
  // conv1d -> cvB (bf16): BM=256, swizzled LDS
  conv_k<<<768, 512, 0, stream>>>(hp, convWt, conv_b, cvB);
  // qkv GEMM: 256x128 swizzled, 384 x 6
  gemm_k<0><<<2304, 512, 0, stream>>>(cvB, 256, qkvWt, qkv_b,
                                      nullptr, qkvB, nullptr, 768, 256, 6);
  // windowed attention -> hp region (attn_out)
  attn_k<<<3072, 256, 0, stream>>>(qkvB, hp);
  // proj + residual(x) + LN2 fused: x1 -> d_out (fp32), ln2 -> hp (bf16)
  proj_ln_k<<<768, 512, 0, stream>>>(hp, projWt, proj_b, x, ln2_g, ln2_b, out, hp);
  // fc1 + fast GELU: 256x128 swizzled, 384 x 8
  gemm_k<2><<<3072, 512, 0, stream>>>(hp, 256, fc1Wt, fc1_b,
                                      nullptr, hidB, nullptr, 1024, 256, 8);
  // fc2 + residual(x1): 256x128 swizzled, 384 x 2, K=1024
  gemm_k<1><<<768, 512, 0, stream>>>(hidB, 1024, fc2Wt, fc2_b,
                                     out, nullptr, out, 256, 1024, 2);
}